// Round 6
// baseline (43.925 us; speedup 1.0000x reference)
//
#include <hip/hip_runtime.h>

#define RSURF 50.0f
#define ETA   (1.0f / 1.5f)

typedef float f32x4 __attribute__((ext_vector_type(4)));

__device__ __forceinline__ void refract_one(float ox, float oy, float dx, float dy,
                                            float cx,
                                            float& px, float& py,
                                            float& rx, float& ry) {
    // ray-circle intersection
    float ocx = ox - cx;
    float ocy = oy;              // center y = 0
    float b = dx * ocx + dy * ocy;
    float c = ocx * ocx + ocy * ocy - RSURF * RSURF;
    float disc = fmaxf(b * b - c, 0.0f);
    float t = -b - sqrtf(disc);
    px = ox + t * dx;
    py = oy + t * dy;

    // outward normal, flipped to oppose incoming ray
    float nx = (px - cx) * (1.0f / RSURF);
    float ny = py * (1.0f / RSURF);
    float dot = nx * dx + ny * dy;
    if (dot > 0.0f) { nx = -nx; ny = -ny; }

    // Snell / TIR
    float cosi  = -(nx * dx + ny * dy);
    float sint2 = ETA * ETA * (1.0f - cosi * cosi);
    float cost  = sqrtf(fmaxf(1.0f - sint2, 0.0f));
    if (sint2 > 1.0f) {
        // reflection (TIR)
        rx = dx + 2.0f * cosi * nx;
        ry = dy + 2.0f * cosi * ny;
    } else {
        float k = ETA * cosi - cost;
        rx = ETA * dx + k * nx;
        ry = ETA * dy + k * ny;
    }
}

__device__ __forceinline__ void do_chunk(const f32x4& o, const f32x4& d, float cx,
                                         f32x4& p, f32x4& r) {
    float p0, p1, p2, p3, r0, r1, r2, r3;
    refract_one(o.x, o.y, d.x, d.y, cx, p0, p1, r0, r1);
    refract_one(o.z, o.w, d.z, d.w, cx, p2, p3, r2, r3);
    p = (f32x4){p0, p1, p2, p3};
    r = (f32x4){r0, r1, r2, r3};
}

// 2 chunks per thread from two far-apart streams: 4x dwordx4 loads in flight
// per thread (2x the MLP of R5), each load 16B/lane coalesced.
__global__ void refractive_surface_kernel(const f32x4* __restrict__ orig,
                                          const f32x4* __restrict__ dirs,
                                          const float* __restrict__ tgt,
                                          f32x4* __restrict__ out_pts,
                                          f32x4* __restrict__ out_ref,
                                          int nchunks /* = n_rays/2 */,
                                          int n_rays) {
    const float cx = tgt[0] + RSURF;   // circle center x (scalar, L2-broadcast)

    int half = (nchunks + 1) >> 1;
    int t = blockIdx.x * blockDim.x + threadIdx.x;

    if (t < half) {
        int j = t + half;
        bool has_j = j < nchunks;

        // issue all loads before any compute (max MLP)
        f32x4 o0 = orig[t];
        f32x4 d0 = dirs[t];
        f32x4 o1 = has_j ? orig[j] : o0;
        f32x4 d1 = has_j ? dirs[j] : d0;

        f32x4 p0, r0, p1, r1;
        do_chunk(o0, d0, cx, p0, r0);
        do_chunk(o1, d1, cx, p1, r1);

        __builtin_nontemporal_store(p0, &out_pts[t]);
        __builtin_nontemporal_store(r0, &out_ref[t]);
        if (has_j) {
            __builtin_nontemporal_store(p1, &out_pts[j]);
            __builtin_nontemporal_store(r1, &out_ref[j]);
        }
    }

    // tail ray if n_rays is odd (not hit for N = 8388608, kept for generality)
    if ((n_rays & 1) && t == 0) {
        int last = n_rays - 1;
        const float* o2 = (const float*)orig;
        const float* d2 = (const float*)dirs;
        float* pp = (float*)out_pts;
        float* rr = (float*)out_ref;
        float px, py, rx, ry;
        refract_one(o2[2 * last], o2[2 * last + 1], d2[2 * last], d2[2 * last + 1],
                    cx, px, py, rx, ry);
        pp[2 * last] = px; pp[2 * last + 1] = py;
        rr[2 * last] = rx; rr[2 * last + 1] = ry;
    }
}

extern "C" void kernel_launch(void* const* d_in, const int* in_sizes, int n_in,
                              void* d_out, int out_size, void* d_ws, size_t ws_size,
                              hipStream_t stream) {
    const f32x4* orig = (const f32x4*)d_in[0];
    const f32x4* dirs = (const f32x4*)d_in[1];
    const float* tgt  = (const float*)d_in[2];

    int n_rays  = in_sizes[0] / 2;   // in_sizes[0] = N*2 flat floats
    int nchunks = n_rays / 2;        // 2 rays per float4
    int half    = (nchunks + 1) >> 1;

    float* out = (float*)d_out;
    f32x4* out_pts = (f32x4*)out;                        // first N*2 floats
    f32x4* out_ref = (f32x4*)(out + 2 * (size_t)n_rays); // next  N*2 floats

    int block = 256;
    int grid  = (half + block - 1) / block;              // 8192 blocks

    refractive_surface_kernel<<<grid, block, 0, stream>>>(
        orig, dirs, tgt, out_pts, out_ref, nchunks, n_rays);
}

// Round 7
// 43.017 us; speedup vs baseline: 1.0211x; 1.0211x over previous
//
#include <hip/hip_runtime.h>

#define RSURF 50.0f
#define ETA   (1.0f / 1.5f)

typedef float f32x4 __attribute__((ext_vector_type(4)));

__device__ __forceinline__ void refract_one(float ox, float oy, float dx, float dy,
                                            float cx,
                                            float& px, float& py,
                                            float& rx, float& ry) {
    // ray-circle intersection
    float ocx = ox - cx;
    float ocy = oy;              // center y = 0
    float b = dx * ocx + dy * ocy;
    float c = ocx * ocx + ocy * ocy - RSURF * RSURF;
    float disc = fmaxf(b * b - c, 0.0f);
    float t = -b - sqrtf(disc);
    px = ox + t * dx;
    py = oy + t * dy;

    // outward normal, flipped to oppose incoming ray
    float nx = (px - cx) * (1.0f / RSURF);
    float ny = py * (1.0f / RSURF);
    float dot = nx * dx + ny * dy;
    if (dot > 0.0f) { nx = -nx; ny = -ny; }

    // Snell / TIR
    float cosi  = -(nx * dx + ny * dy);
    float sint2 = ETA * ETA * (1.0f - cosi * cosi);
    float cost  = sqrtf(fmaxf(1.0f - sint2, 0.0f));
    if (sint2 > 1.0f) {
        // reflection (TIR)
        rx = dx + 2.0f * cosi * nx;
        ry = dy + 2.0f * cosi * ny;
    } else {
        float k = ETA * cosi - cost;
        rx = ETA * dx + k * nx;
        ry = ETA * dy + k * ny;
    }
}

// One chunk (2 rays) per thread, exact grid: proven best (R5, 42.8 us =
// 99.5% of the 6.29 TB/s measured mixed-stream ceiling at 268 MB logical).
__global__ void refractive_surface_kernel(const f32x4* __restrict__ orig,
                                          const f32x4* __restrict__ dirs,
                                          const float* __restrict__ tgt,
                                          f32x4* __restrict__ out_pts,
                                          f32x4* __restrict__ out_ref,
                                          int nchunks /* = n_rays/2 */,
                                          int n_rays) {
    const float cx = tgt[0] + RSURF;   // circle center x (scalar, L2-broadcast)

    int i = blockIdx.x * blockDim.x + threadIdx.x;
    if (i < nchunks) {
        f32x4 o = orig[i];   // 2 rays: (o.x,o.y) and (o.z,o.w)
        f32x4 d = dirs[i];
        float p0, p1, p2, p3, r0, r1, r2, r3;
        refract_one(o.x, o.y, d.x, d.y, cx, p0, p1, r0, r1);
        refract_one(o.z, o.w, d.z, d.w, cx, p2, p3, r2, r3);
        f32x4 p = {p0, p1, p2, p3};
        f32x4 r = {r0, r1, r2, r3};
        __builtin_nontemporal_store(p, &out_pts[i]);
        __builtin_nontemporal_store(r, &out_ref[i]);
    }

    // tail ray if n_rays is odd (not hit for N = 8388608, kept for generality)
    if ((n_rays & 1) && i == 0) {
        int last = n_rays - 1;
        const float* o2 = (const float*)orig;
        const float* d2 = (const float*)dirs;
        float* pp = (float*)out_pts;
        float* rr = (float*)out_ref;
        float px, py, rx, ry;
        refract_one(o2[2 * last], o2[2 * last + 1], d2[2 * last], d2[2 * last + 1],
                    cx, px, py, rx, ry);
        pp[2 * last] = px; pp[2 * last + 1] = py;
        rr[2 * last] = rx; rr[2 * last + 1] = ry;
    }
}

extern "C" void kernel_launch(void* const* d_in, const int* in_sizes, int n_in,
                              void* d_out, int out_size, void* d_ws, size_t ws_size,
                              hipStream_t stream) {
    const f32x4* orig = (const f32x4*)d_in[0];
    const f32x4* dirs = (const f32x4*)d_in[1];
    const float* tgt  = (const float*)d_in[2];

    int n_rays  = in_sizes[0] / 2;   // in_sizes[0] = N*2 flat floats
    int nchunks = n_rays / 2;        // 2 rays per float4

    float* out = (float*)d_out;
    f32x4* out_pts = (f32x4*)out;                        // first N*2 floats
    f32x4* out_ref = (f32x4*)(out + 2 * (size_t)n_rays); // next  N*2 floats

    int block = 256;
    int grid  = (nchunks + block - 1) / block;           // exact grid: 16384 blocks

    refractive_surface_kernel<<<grid, block, 0, stream>>>(
        orig, dirs, tgt, out_pts, out_ref, nchunks, n_rays);
}